// Round 2
// baseline (1197.158 us; speedup 1.0000x reference)
//
#include <hip/hip_runtime.h>
#include <math.h>

#define NA 100000
#define NE 800000

typedef __attribute__((ext_vector_type(8))) short short8;
typedef __attribute__((ext_vector_type(4))) float f32x4;

// ---- monotone float<->uint map for atomicMax on floats ----
__device__ __forceinline__ unsigned fmap(float f) {
    unsigned b = __float_as_uint(f);
    return (b & 0x80000000u) ? ~b : (b | 0x80000000u);
}
__device__ __forceinline__ float funmap(unsigned u) {
    unsigned b = (u & 0x80000000u) ? (u ^ 0x80000000u) : ~u;
    return __uint_as_float(b);
}
// f32 -> bf16 RNE bits
__device__ __forceinline__ unsigned short f2bf(float f) {
    unsigned u = __float_as_uint(f);
    u += 0x7fffu + ((u >> 16) & 1u);
    return (unsigned short)(u >> 16);
}
__device__ __forceinline__ unsigned pkbf(float lo, float hi) {
    return (unsigned)f2bf(lo) | ((unsigned)f2bf(hi) << 16);
}
union FragU { unsigned u[4]; short8 s; };
// 8 consecutive f32 -> bf16x8 frag (element j = k-offset j)
__device__ __forceinline__ short8 pack_frag(float4 a, float4 b) {
    FragU r;
    r.u[0] = pkbf(a.x, a.y);
    r.u[1] = pkbf(a.z, a.w);
    r.u[2] = pkbf(b.x, b.y);
    r.u[3] = pkbf(b.z, b.w);
    return r.s;
}
__device__ __forceinline__ short8 ldsfrag(const unsigned short* p) {
    return *(const short8*)p;
}
__device__ __forceinline__ float4 add4(float4 a, float4 b) {
    return make_float4(a.x + b.x, a.y + b.y, a.z + b.z, a.w + b.w);
}
// pack 16 consecutive floats (4 float4s) into 8 bf16x2 words
__device__ __forceinline__ void pack8(float4 A, float4 B, float4 C, float4 D,
                                      unsigned (&u)[8]) {
    u[0] = pkbf(A.x, A.y); u[1] = pkbf(A.z, A.w);
    u[2] = pkbf(B.x, B.y); u[3] = pkbf(B.z, B.w);
    u[4] = pkbf(C.x, C.y); u[5] = pkbf(C.z, C.w);
    u[6] = pkbf(D.x, D.y); u[7] = pkbf(D.z, D.w);
}
// Redistribute coalesced-loaded row data to B-frag ownership.
// Loader lane 4e+p holds row e floats [16p..16p+15] packed in u[0..7].
// Target lane (l15,lq) needs floats [8lq..8lq+7] (f0) and [32+8lq..+7] (f1) of row l15:
//   src lane = 4*l15 + (lq>>1) (+2 for f1), word index = 4*(lq&1)+i.
__device__ __forceinline__ void redist(const unsigned (&u)[8], int srcA, bool hi,
                                       short8& f0, short8& f1) {
    FragU r0, r1;
#pragma unroll
    for (int i = 0; i < 4; i++) {
        unsigned lo0 = __shfl(u[i],     srcA);
        unsigned hi0 = __shfl(u[4 + i], srcA);
        unsigned lo1 = __shfl(u[i],     srcA + 2);
        unsigned hi1 = __shfl(u[4 + i], srcA + 2);
        r0.u[i] = hi ? hi0 : lo0;
        r1.u[i] = hi ? hi1 : lo1;
    }
    f0 = r0.s;
    f1 = r1.s;
}

// 4-lane transpose between layers.
// In: P[t][p] at lane (lq,l15) = bf16x2 of h[edge l15][n=16t+4lq+2p (+1)]
// Out: a0/a1 = frag of h for next layer (K=64): lane holds h[edge l15][32ks+8lq+j].
__device__ __forceinline__ void trans4(const unsigned (&P)[4][2], int lq, int l15,
                                       short8& a0, short8& a1) {
    FragU r0, r1;
    int up = (lq >> 1) & 1;
#pragma unroll
    for (int jj = 0; jj < 4; jj++) {
        int srcl = l15 + ((2 * (lq & 1) + (jj >> 1)) << 4);
        unsigned q0 = __shfl(P[0][jj & 1], srcl);
        unsigned q1 = __shfl(P[1][jj & 1], srcl);
        unsigned q2 = __shfl(P[2][jj & 1], srcl);
        unsigned q3 = __shfl(P[3][jj & 1], srcl);
        r0.u[jj] = up ? q1 : q0;
        r1.u[jj] = up ? q3 : q2;
    }
    a0 = r0.s;
    a1 = r1.s;
}

// ---- v = atom_feat @ Wv + bv  (N x 8) ----
__global__ void k_v(const float* __restrict__ af, const float* __restrict__ Wv,
                    const float* __restrict__ bv, float* __restrict__ v) {
    __shared__ float sWv[512];
    __shared__ float sbv[8];
    int t = threadIdx.x;
    for (int i = t; i < 512; i += 256) sWv[i] = Wv[i];
    if (t < 8) sbv[t] = bv[t];
    __syncthreads();
    int gid = blockIdx.x * 256 + t;
    if (gid >= NA * 8) return;
    int n = gid >> 3, i = gid & 7;
    const float* ar = af + (long)n * 64;
    float acc = sbv[i];
#pragma unroll
    for (int k = 0; k < 64; k++) acc += ar[k] * sWv[k * 8 + i];
    v[gid] = acc;
}

// ---- edge MLP, transposed compute: C = W^T @ x^T ----
// Coalesced cooperative gather of af rows + in-wave shfl redistribution to frags.
__global__ __launch_bounds__(256, 4) void k_edge_mlp(
    const float* __restrict__ af, const float* __restrict__ bond,
    const int* __restrict__ eidx,
    const float* __restrict__ W1, const float* __restrict__ b1,
    const float* __restrict__ W2, const float* __restrict__ b2,
    const float* __restrict__ W3, const float* __restrict__ b3,
    float* __restrict__ logits, unsigned* __restrict__ segmax) {
    // B-frag order: [n-tile][kchunk][n16 ^ swz][8k]
    __shared__ __align__(16) unsigned short sW1T[4][24][16][8];   // 24.0 KB
    __shared__ __align__(16) unsigned short sW2T[4][8][16][8];    //  8.0 KB
    __shared__ __align__(16) unsigned short sW3T[8][16][8];       //  2.0 KB
    __shared__ __align__(16) float sb1[64], sb2[64], sb3[8];

    int tid = threadIdx.x;
    for (int idx = tid; idx < 192 * 64; idx += 256) {
        int k = idx >> 6, n = idx & 63, kc = k >> 3;
        sW1T[n >> 4][kc][(n & 15) ^ ((kc & 3) << 1)][k & 7] = f2bf(W1[idx]);
    }
    for (int idx = tid; idx < 64 * 64; idx += 256) {
        int k = idx >> 6, n = idx & 63, kc = k >> 3;
        sW2T[n >> 4][kc][(n & 15) ^ ((kc & 3) << 1)][k & 7] = f2bf(W2[idx]);
    }
    for (int idx = tid; idx < 8 * 16 * 8; idx += 256) ((unsigned short*)sW3T)[idx] = 0;
    if (tid < 64) { sb1[tid] = b1[tid]; sb2[tid] = b2[tid]; }
    if (tid < 8) sb3[tid] = b3[tid];
    __syncthreads();
    for (int idx = tid; idx < 64 * 8; idx += 256) {
        int k = idx >> 3, o = idx & 7, kc = k >> 3;
        sW3T[kc][o ^ ((kc & 3) << 1)][k & 7] = f2bf(W3[idx]);
    }
    __syncthreads();

    int lane = tid & 63, wv = tid >> 6;
    int l15 = lane & 15, lq = lane >> 4;
    int swz = l15 ^ (lq << 1);
    int eL  = lane >> 2;              // edge this lane gathers (cooperative)
    int part = lane & 3;              // which 16-float quarter of the row
    int srcA = (l15 << 2) + (lq >> 1);
    bool hi  = (lq & 1) != 0;

    long stride = (long)gridDim.x * 4;
    for (long tile = (long)blockIdx.x * 4 + wv; tile < NE / 16; tile += stride) {
        long base = tile * 16;
        long e = base + l15;          // frag-owner edge of this lane
        // ---- coalesced gather: lane reads 64B contiguous of row (edge eL) ----
        int2 sd = ((const int2*)eidx)[base + eL];
        const float4* pdq = (const float4*)(af + (long)sd.y * 64) + part * 4;
        float4 d0 = pdq[0], d1 = pdq[1], d2 = pdq[2], d3 = pdq[3];
        const float4* psq = (const float4*)(af + (long)sd.x * 64) + part * 4;
        float4 s0 = psq[0], s1 = psq[1], s2 = psq[2], s3 = psq[3];
        const float* pb = bond + e * 64 + lq * 8;    // contiguous per lane
        float4 c0 = *(const float4*)(pb);
        float4 c1 = *(const float4*)(pb + 4);
        float4 c2 = *(const float4*)(pb + 32);
        float4 c3 = *(const float4*)(pb + 36);

        unsigned ud[8], us[8];
        pack8(d0, d1, d2, d3, ud);
        pack8(s0, s1, s2, s3, us);
        short8 xf0, xf1, xf2, xf3;
        redist(ud, srcA, hi, xf0, xf1);   // dst row -> k 0..63
        redist(us, srcA, hi, xf2, xf3);   // src row -> k 64..127
        short8 xf4 = pack_frag(c0, c1);   // bond    -> k 128..159
        short8 xf5 = pack_frag(c2, c3);   //            k 160..191
        int esrc = __shfl(sd.x, l15 << 2);   // src node of frag-owner edge l15

        // ---- layer 1: W1^T(64x192) @ x^T(192x16) ----
        f32x4 acc[4] = {{0,0,0,0},{0,0,0,0},{0,0,0,0},{0,0,0,0}};
#pragma unroll
        for (int t = 0; t < 4; t++) {
            acc[t] = __builtin_amdgcn_mfma_f32_16x16x32_bf16(ldsfrag(&sW1T[t][lq][swz][0]),      xf0, acc[t], 0, 0, 0);
            acc[t] = __builtin_amdgcn_mfma_f32_16x16x32_bf16(ldsfrag(&sW1T[t][4 + lq][swz][0]),  xf1, acc[t], 0, 0, 0);
            acc[t] = __builtin_amdgcn_mfma_f32_16x16x32_bf16(ldsfrag(&sW1T[t][8 + lq][swz][0]),  xf2, acc[t], 0, 0, 0);
            acc[t] = __builtin_amdgcn_mfma_f32_16x16x32_bf16(ldsfrag(&sW1T[t][12 + lq][swz][0]), xf3, acc[t], 0, 0, 0);
            acc[t] = __builtin_amdgcn_mfma_f32_16x16x32_bf16(ldsfrag(&sW1T[t][16 + lq][swz][0]), xf4, acc[t], 0, 0, 0);
            acc[t] = __builtin_amdgcn_mfma_f32_16x16x32_bf16(ldsfrag(&sW1T[t][20 + lq][swz][0]), xf5, acc[t], 0, 0, 0);
        }
        unsigned P[4][2];
#pragma unroll
        for (int t = 0; t < 4; t++) {
            float4 bb = *(const float4*)&sb1[t * 16 + lq * 4];
            float h0  = fmaxf(acc[t][0] + bb.x, 0.f);
            float h1v = fmaxf(acc[t][1] + bb.y, 0.f);
            float h2v = fmaxf(acc[t][2] + bb.z, 0.f);
            float h3v = fmaxf(acc[t][3] + bb.w, 0.f);
            P[t][0] = pkbf(h0, h1v);
            P[t][1] = pkbf(h2v, h3v);
        }
        short8 a0, a1;
        trans4(P, lq, l15, a0, a1);

        // ---- layer 2: W2^T(64x64) @ h1^T ----
        f32x4 ac2[4] = {{0,0,0,0},{0,0,0,0},{0,0,0,0},{0,0,0,0}};
#pragma unroll
        for (int t = 0; t < 4; t++) {
            ac2[t] = __builtin_amdgcn_mfma_f32_16x16x32_bf16(ldsfrag(&sW2T[t][lq][swz][0]),     a0, ac2[t], 0, 0, 0);
            ac2[t] = __builtin_amdgcn_mfma_f32_16x16x32_bf16(ldsfrag(&sW2T[t][4 + lq][swz][0]), a1, ac2[t], 0, 0, 0);
        }
#pragma unroll
        for (int t = 0; t < 4; t++) {
            float4 bb = *(const float4*)&sb2[t * 16 + lq * 4];
            float h0  = fmaxf(ac2[t][0] + bb.x, 0.f);
            float h1v = fmaxf(ac2[t][1] + bb.y, 0.f);
            float h2v = fmaxf(ac2[t][2] + bb.z, 0.f);
            float h3v = fmaxf(ac2[t][3] + bb.w, 0.f);
            P[t][0] = pkbf(h0, h1v);
            P[t][1] = pkbf(h2v, h3v);
        }
        trans4(P, lq, l15, a0, a1);

        // ---- layer 3: W3^T(8x64, zero-padded) @ h2^T ----
        f32x4 aL = {0, 0, 0, 0};
        aL = __builtin_amdgcn_mfma_f32_16x16x32_bf16(ldsfrag(&sW3T[lq][swz][0]),     a0, aL, 0, 0, 0);
        aL = __builtin_amdgcn_mfma_f32_16x16x32_bf16(ldsfrag(&sW3T[4 + lq][swz][0]), a1, aL, 0, 0, 0);
        if (lq < 2) {
            float4 bb = *(const float4*)&sb3[lq * 4];
            float4 lg;
            lg.x = aL[0] + bb.x;
            lg.y = aL[1] + bb.y;
            lg.z = aL[2] + bb.z;
            lg.w = aL[3] + bb.w;
            *(float4*)(logits + e * 8 + lq * 4) = lg;
            unsigned* sm = segmax + (long)esrc * 8 + lq * 4;
            atomicMax(sm + 0, fmap(lg.x));
            atomicMax(sm + 1, fmap(lg.y));
            atomicMax(sm + 2, fmap(lg.z));
            atomicMax(sm + 3, fmap(lg.w));
        }
    }
}

// ---- fused: e=exp(lg-max); denom[src]+=e; agg[src] += e * v[dst] (unnormalized) ----
__global__ void k_agg(const int* __restrict__ eidx,
                      const float* __restrict__ logits,
                      const unsigned* __restrict__ segmax,
                      const float* __restrict__ v,
                      float* __restrict__ denom,
                      float* __restrict__ agg) {
    int t = threadIdx.x;
    int lane = t & 63, wv = t >> 6;
    long e = (long)blockIdx.x * 4 + wv;
    if (e >= NE) return;
    int2 sd = ((const int2*)eidx)[e];
    int o = lane & 7;      // head index j
    int i = lane >> 3;     // value index
    float lg = logits[e * 8 + o];
    float m = funmap(segmax[(long)sd.x * 8 + o]);
    float ex = __expf(lg - m);
    if (i == 0) atomicAdd(&denom[(long)sd.x * 8 + o], ex);
    float val = ex * v[(long)sd.y * 8 + i];
    atomicAdd(&agg[(long)sd.x * 64 + lane], val);
}

// ---- out_pre = (agg/denom)@Wc+bc ; out_final = relu(af + out_pre) ----
__global__ __launch_bounds__(256) void k_out(
    const float* __restrict__ agg, const float* __restrict__ denom,
    const float* __restrict__ Wc, const float* __restrict__ bc,
    const float* __restrict__ af,
    float* __restrict__ out_pre, float* __restrict__ out_final) {
    __shared__ float sWc[64 * 64];
    int t = threadIdx.x;
    for (int i = t; i < 4096; i += 256) sWc[i] = Wc[i];
    __syncthreads();
    int lane = t & 63, wv = t >> 6;
    float bcv = bc[lane];
    long stride = (long)gridDim.x * 4;
    for (long n = (long)blockIdx.x * 4 + wv; n < NA; n += stride) {
        float den = denom[n * 8 + (lane & 7)];
        float rs = (den != 0.f) ? (1.0f / den) : 0.f;   // deg-0 node: agg==0, avoid 0*inf
        float a = agg[n * 64 + lane] * rs;
        float acc = bcv;
#pragma unroll 4
        for (int k = 0; k < 64; k++) acc += __shfl(a, k) * sWc[k * 64 + lane];
        out_pre[n * 64 + lane] = acc;
        out_final[n * 64 + lane] = fmaxf(af[n * 64 + lane] + acc, 0.f);
    }
}

// ---- new_bond = relu([op[dst]+op[src], bond] @ Wb + bb) ----
// Coalesced gather of out_pre rows, summed at loader lane, shfl-redistributed.
__global__ __launch_bounds__(256, 4) void k_bond_out(
    const float* __restrict__ out_pre, const float* __restrict__ bond,
    const int* __restrict__ eidx, const float* __restrict__ Wb,
    const float* __restrict__ bb, float* __restrict__ nbf) {
    __shared__ __align__(16) unsigned short sWbT[4][16][16][8];   // 16 KB
    __shared__ __align__(16) float sbb[64];

    int tid = threadIdx.x;
    for (int idx = tid; idx < 128 * 64; idx += 256) {
        int k = idx >> 6, n = idx & 63, kc = k >> 3;
        sWbT[n >> 4][kc][(n & 15) ^ ((kc & 3) << 1)][k & 7] = f2bf(Wb[idx]);
    }
    if (tid < 64) sbb[tid] = bb[tid];
    __syncthreads();

    int lane = tid & 63, wv = tid >> 6;
    int l15 = lane & 15, lq = lane >> 4;
    int swz = l15 ^ (lq << 1);
    int eL  = lane >> 2;
    int part = lane & 3;
    int srcA = (l15 << 2) + (lq >> 1);
    bool hi  = (lq & 1) != 0;

    long stride = (long)gridDim.x * 4;
    for (long tile = (long)blockIdx.x * 4 + wv; tile < NE / 16; tile += stride) {
        long base = tile * 16;
        long e = base + l15;
        // ---- coalesced gather + sum at loader lane ----
        int2 sd = ((const int2*)eidx)[base + eL];
        const float4* pdq = (const float4*)(out_pre + (long)sd.y * 64) + part * 4;
        const float4* psq = (const float4*)(out_pre + (long)sd.x * 64) + part * 4;
        float4 q0 = add4(pdq[0], psq[0]);
        float4 q1 = add4(pdq[1], psq[1]);
        float4 q2 = add4(pdq[2], psq[2]);
        float4 q3 = add4(pdq[3], psq[3]);
        unsigned uo[8];
        pack8(q0, q1, q2, q3, uo);
        short8 xf0, xf1;
        redist(uo, srcA, hi, xf0, xf1);   // (op[dst]+op[src]) -> k 0..63

        const float* pb = bond + e * 64 + lq * 8;
        float4 c0 = *(const float4*)(pb);
        float4 c1 = *(const float4*)(pb + 4);
        float4 c2 = *(const float4*)(pb + 32);
        float4 c3 = *(const float4*)(pb + 36);
        short8 xf2 = pack_frag(c0, c1);   // bond -> k 64..95
        short8 xf3 = pack_frag(c2, c3);   //         k 96..127

        f32x4 acc[4] = {{0,0,0,0},{0,0,0,0},{0,0,0,0},{0,0,0,0}};
#pragma unroll
        for (int t = 0; t < 4; t++) {
            acc[t] = __builtin_amdgcn_mfma_f32_16x16x32_bf16(ldsfrag(&sWbT[t][lq][swz][0]),      xf0, acc[t], 0, 0, 0);
            acc[t] = __builtin_amdgcn_mfma_f32_16x16x32_bf16(ldsfrag(&sWbT[t][4 + lq][swz][0]),  xf1, acc[t], 0, 0, 0);
            acc[t] = __builtin_amdgcn_mfma_f32_16x16x32_bf16(ldsfrag(&sWbT[t][8 + lq][swz][0]),  xf2, acc[t], 0, 0, 0);
            acc[t] = __builtin_amdgcn_mfma_f32_16x16x32_bf16(ldsfrag(&sWbT[t][12 + lq][swz][0]), xf3, acc[t], 0, 0, 0);
        }
        float* op = nbf + e * 64 + lq * 4;
#pragma unroll
        for (int t = 0; t < 4; t++) {
            float4 bq = *(const float4*)&sbb[t * 16 + lq * 4];
            float4 r;
            r.x = fmaxf(acc[t][0] + bq.x, 0.f);
            r.y = fmaxf(acc[t][1] + bq.y, 0.f);
            r.z = fmaxf(acc[t][2] + bq.z, 0.f);
            r.w = fmaxf(acc[t][3] + bq.w, 0.f);
            *(float4*)(op + t * 16) = r;
        }
    }
}

extern "C" void kernel_launch(void* const* d_in, const int* in_sizes, int n_in,
                              void* d_out, int out_size, void* d_ws, size_t ws_size,
                              hipStream_t stream) {
    const float* af   = (const float*)d_in[0];
    const float* bond = (const float*)d_in[1];
    const int*   eidx = (const int*)d_in[2];
    const float* Wv = (const float*)d_in[3];
    const float* bv = (const float*)d_in[4];
    const float* W1 = (const float*)d_in[5];
    const float* b1 = (const float*)d_in[6];
    const float* W2 = (const float*)d_in[7];
    const float* b2 = (const float*)d_in[8];
    const float* W3 = (const float*)d_in[9];
    const float* b3 = (const float*)d_in[10];
    const float* Wc = (const float*)d_in[11];
    const float* bc = (const float*)d_in[12];
    const float* Wb = (const float*)d_in[13];
    const float* bb = (const float*)d_in[14];

    float* out_final = (float*)d_out;                  // N*64
    float* nbf       = (float*)d_out + (long)NA * 64;  // E*64

    float* ws = (float*)d_ws;
    float*    v       = ws;                         // N*8
    unsigned* segmax  = (unsigned*)(ws + 800000);   // N*8
    float*    denom   = ws + 1600000;               // N*8
    float*    logits  = ws + 2400000;               // E*8
    float*    agg     = ws + 8800000;               // N*64
    float*    out_pre = ws + 15200000;              // N*64

    // one memset covers segmax (800k u32) + denom (800k f32), contiguous
    hipMemsetAsync((void*)segmax, 0, (size_t)1600000 * 4, stream);
    hipMemsetAsync((void*)agg, 0, (size_t)6400000 * 4, stream);

    k_v<<<(NA * 8 + 255) / 256, 256, 0, stream>>>(af, Wv, bv, v);

    k_edge_mlp<<<1024, 256, 0, stream>>>(af, bond, eidx, W1, b1, W2, b2, W3, b3,
                                         logits, segmax);

    k_agg<<<NE / 4, 256, 0, stream>>>(eidx, logits, segmax, v, denom, agg);

    k_out<<<512, 256, 0, stream>>>(agg, denom, Wc, bc, af, out_pre, out_final);

    k_bond_out<<<2048, 256, 0, stream>>>(out_pre, bond, eidx, Wb, bb, nbf);
}

// Round 5
// 982.761 us; speedup vs baseline: 1.2182x; 1.2182x over previous
//
#include <hip/hip_runtime.h>
#include <math.h>

#define NA 100000
#define NE 800000

typedef __attribute__((ext_vector_type(8))) short short8;
typedef __attribute__((ext_vector_type(4))) float f32x4;

// ---- monotone float<->uint map for atomicMax on floats ----
__device__ __forceinline__ unsigned fmap(float f) {
    unsigned b = __float_as_uint(f);
    return (b & 0x80000000u) ? ~b : (b | 0x80000000u);
}
__device__ __forceinline__ float funmap(unsigned u) {
    unsigned b = (u & 0x80000000u) ? (u ^ 0x80000000u) : ~u;
    return __uint_as_float(b);
}
// f32 -> bf16 RNE bits
__device__ __forceinline__ unsigned short f2bf(float f) {
    unsigned u = __float_as_uint(f);
    u += 0x7fffu + ((u >> 16) & 1u);
    return (unsigned short)(u >> 16);
}
__device__ __forceinline__ unsigned pkbf(float lo, float hi) {
    return (unsigned)f2bf(lo) | ((unsigned)f2bf(hi) << 16);
}
union FragU { unsigned u[4]; short8 s; };
// 8 consecutive f32 -> bf16x8 frag (element j = k-offset j)
__device__ __forceinline__ short8 pack_frag(float4 a, float4 b) {
    FragU r;
    r.u[0] = pkbf(a.x, a.y);
    r.u[1] = pkbf(a.z, a.w);
    r.u[2] = pkbf(b.x, b.y);
    r.u[3] = pkbf(b.z, b.w);
    return r.s;
}
__device__ __forceinline__ short8 ldsfrag(const unsigned short* p) {
    return *(const short8*)p;
}
__device__ __forceinline__ float4 add4(float4 a, float4 b) {
    return make_float4(a.x + b.x, a.y + b.y, a.z + b.z, a.w + b.w);
}
// pack 16 consecutive floats (4 float4s) into 8 bf16x2 words
__device__ __forceinline__ void pack8(float4 A, float4 B, float4 C, float4 D,
                                      unsigned (&u)[8]) {
    u[0] = pkbf(A.x, A.y); u[1] = pkbf(A.z, A.w);
    u[2] = pkbf(B.x, B.y); u[3] = pkbf(B.z, B.w);
    u[4] = pkbf(C.x, C.y); u[5] = pkbf(C.z, C.w);
    u[6] = pkbf(D.x, D.y); u[7] = pkbf(D.z, D.w);
}
// Redistribute coalesced-loaded row data to B-frag ownership.
// Loader lane 4e+p holds row e floats [16p..16p+15] packed in u[0..7].
// Target lane (l15,lq) needs floats [8lq..8lq+7] (f0) and [32+8lq..+7] (f1) of row l15:
//   src lane = 4*l15 + (lq>>1) (+2 for f1), word index = 4*(lq&1)+i.
__device__ __forceinline__ void redist(const unsigned (&u)[8], int srcA, bool hi,
                                       short8& f0, short8& f1) {
    FragU r0, r1;
#pragma unroll
    for (int i = 0; i < 4; i++) {
        unsigned lo0 = __shfl(u[i],     srcA);
        unsigned hi0 = __shfl(u[4 + i], srcA);
        unsigned lo1 = __shfl(u[i],     srcA + 2);
        unsigned hi1 = __shfl(u[4 + i], srcA + 2);
        r0.u[i] = hi ? hi0 : lo0;
        r1.u[i] = hi ? hi1 : lo1;
    }
    f0 = r0.s;
    f1 = r1.s;
}

// 4-lane transpose between layers.
// In: P[t][p] at lane (lq,l15) = bf16x2 of h[edge l15][n=16t+4lq+2p (+1)]
// Out: a0/a1 = frag of h for next layer (K=64): lane holds h[edge l15][32ks+8lq+j].
__device__ __forceinline__ void trans4(const unsigned (&P)[4][2], int lq, int l15,
                                       short8& a0, short8& a1) {
    FragU r0, r1;
    int up = (lq >> 1) & 1;
#pragma unroll
    for (int jj = 0; jj < 4; jj++) {
        int srcl = l15 + ((2 * (lq & 1) + (jj >> 1)) << 4);
        unsigned q0 = __shfl(P[0][jj & 1], srcl);
        unsigned q1 = __shfl(P[1][jj & 1], srcl);
        unsigned q2 = __shfl(P[2][jj & 1], srcl);
        unsigned q3 = __shfl(P[3][jj & 1], srcl);
        r0.u[jj] = up ? q1 : q0;
        r1.u[jj] = up ? q3 : q2;
    }
    a0 = r0.s;
    a1 = r1.s;
}

// ---- v = atom_feat @ Wv + bv  (N x 8) ----
__global__ void k_v(const float* __restrict__ af, const float* __restrict__ Wv,
                    const float* __restrict__ bv, float* __restrict__ v) {
    __shared__ float sWv[512];
    __shared__ float sbv[8];
    int t = threadIdx.x;
    for (int i = t; i < 512; i += 256) sWv[i] = Wv[i];
    if (t < 8) sbv[t] = bv[t];
    __syncthreads();
    int gid = blockIdx.x * 256 + t;
    if (gid >= NA * 8) return;
    int n = gid >> 3, i = gid & 7;
    const float* ar = af + (long)n * 64;
    float acc = sbv[i];
#pragma unroll
    for (int k = 0; k < 64; k++) acc += ar[k] * sWv[k * 8 + i];
    v[gid] = acc;
}

// ---- edge MLP, transposed compute: C = W^T @ x^T ----
// Coalesced cooperative gather of af rows + in-wave shfl redistribution to frags.
// NOTE: plain __launch_bounds__(256) — the (256,4) hint squeezed the allocator
// to 64 VGPRs and caused heavy scratch spills (FETCH+650MB, WRITE+180MB in R1/R2).
__global__ __launch_bounds__(256) void k_edge_mlp(
    const float* __restrict__ af, const float* __restrict__ bond,
    const int* __restrict__ eidx,
    const float* __restrict__ W1, const float* __restrict__ b1,
    const float* __restrict__ W2, const float* __restrict__ b2,
    const float* __restrict__ W3, const float* __restrict__ b3,
    float* __restrict__ logits, unsigned* __restrict__ segmax) {
    // B-frag order: [n-tile][kchunk][n16 ^ swz][8k]
    __shared__ __align__(16) unsigned short sW1T[4][24][16][8];   // 24.0 KB
    __shared__ __align__(16) unsigned short sW2T[4][8][16][8];    //  8.0 KB
    __shared__ __align__(16) unsigned short sW3T[8][16][8];       //  2.0 KB
    __shared__ __align__(16) float sb1[64], sb2[64], sb3[8];

    int tid = threadIdx.x;
    for (int idx = tid; idx < 192 * 64; idx += 256) {
        int k = idx >> 6, n = idx & 63, kc = k >> 3;
        sW1T[n >> 4][kc][(n & 15) ^ ((kc & 3) << 1)][k & 7] = f2bf(W1[idx]);
    }
    for (int idx = tid; idx < 64 * 64; idx += 256) {
        int k = idx >> 6, n = idx & 63, kc = k >> 3;
        sW2T[n >> 4][kc][(n & 15) ^ ((kc & 3) << 1)][k & 7] = f2bf(W2[idx]);
    }
    for (int idx = tid; idx < 8 * 16 * 8; idx += 256) ((unsigned short*)sW3T)[idx] = 0;
    if (tid < 64) { sb1[tid] = b1[tid]; sb2[tid] = b2[tid]; }
    if (tid < 8) sb3[tid] = b3[tid];
    __syncthreads();
    for (int idx = tid; idx < 64 * 8; idx += 256) {
        int k = idx >> 3, o = idx & 7, kc = k >> 3;
        sW3T[kc][o ^ ((kc & 3) << 1)][k & 7] = f2bf(W3[idx]);
    }
    __syncthreads();

    int lane = tid & 63, wv = tid >> 6;
    int l15 = lane & 15, lq = lane >> 4;
    int swz = l15 ^ (lq << 1);
    int eL  = lane >> 2;              // edge this lane gathers (cooperative)
    int part = lane & 3;              // which 64B quarter of the row
    int srcA = (l15 << 2) + (lq >> 1);
    bool hi  = (lq & 1) != 0;

    long stride = (long)gridDim.x * 4;
    for (long tile = (long)blockIdx.x * 4 + wv; tile < NE / 16; tile += stride) {
        long base = tile * 16;
        long e = base + l15;          // frag-owner edge of this lane
        // ---- coalesced gather: lane reads 64B contiguous of row (edge eL) ----
        int2 sd = ((const int2*)eidx)[base + eL];
        const float4* pdq = (const float4*)(af + (long)sd.y * 64) + part * 4;
        float4 d0 = pdq[0], d1 = pdq[1], d2 = pdq[2], d3 = pdq[3];
        const float4* psq = (const float4*)(af + (long)sd.x * 64) + part * 4;
        float4 s0 = psq[0], s1 = psq[1], s2 = psq[2], s3 = psq[3];
        const float* pb = bond + e * 64 + lq * 8;    // contiguous per lane
        float4 c0 = *(const float4*)(pb);
        float4 c1 = *(const float4*)(pb + 4);
        float4 c2 = *(const float4*)(pb + 32);
        float4 c3 = *(const float4*)(pb + 36);

        unsigned ud[8], us[8];
        pack8(d0, d1, d2, d3, ud);
        pack8(s0, s1, s2, s3, us);
        short8 xf0, xf1, xf2, xf3;
        redist(ud, srcA, hi, xf0, xf1);   // dst row -> k 0..63
        redist(us, srcA, hi, xf2, xf3);   // src row -> k 64..127
        short8 xf4 = pack_frag(c0, c1);   // bond    -> k 128..159
        short8 xf5 = pack_frag(c2, c3);   //            k 160..191
        int esrc = __shfl(sd.x, l15 << 2);   // src node of frag-owner edge l15

        // ---- layer 1: W1^T(64x192) @ x^T(192x16) ----
        f32x4 acc[4] = {{0,0,0,0},{0,0,0,0},{0,0,0,0},{0,0,0,0}};
#pragma unroll
        for (int t = 0; t < 4; t++) {
            acc[t] = __builtin_amdgcn_mfma_f32_16x16x32_bf16(ldsfrag(&sW1T[t][lq][swz][0]),      xf0, acc[t], 0, 0, 0);
            acc[t] = __builtin_amdgcn_mfma_f32_16x16x32_bf16(ldsfrag(&sW1T[t][4 + lq][swz][0]),  xf1, acc[t], 0, 0, 0);
            acc[t] = __builtin_amdgcn_mfma_f32_16x16x32_bf16(ldsfrag(&sW1T[t][8 + lq][swz][0]),  xf2, acc[t], 0, 0, 0);
            acc[t] = __builtin_amdgcn_mfma_f32_16x16x32_bf16(ldsfrag(&sW1T[t][12 + lq][swz][0]), xf3, acc[t], 0, 0, 0);
            acc[t] = __builtin_amdgcn_mfma_f32_16x16x32_bf16(ldsfrag(&sW1T[t][16 + lq][swz][0]), xf4, acc[t], 0, 0, 0);
            acc[t] = __builtin_amdgcn_mfma_f32_16x16x32_bf16(ldsfrag(&sW1T[t][20 + lq][swz][0]), xf5, acc[t], 0, 0, 0);
        }
        unsigned P[4][2];
#pragma unroll
        for (int t = 0; t < 4; t++) {
            float4 bb = *(const float4*)&sb1[t * 16 + lq * 4];
            float h0  = fmaxf(acc[t][0] + bb.x, 0.f);
            float h1v = fmaxf(acc[t][1] + bb.y, 0.f);
            float h2v = fmaxf(acc[t][2] + bb.z, 0.f);
            float h3v = fmaxf(acc[t][3] + bb.w, 0.f);
            P[t][0] = pkbf(h0, h1v);
            P[t][1] = pkbf(h2v, h3v);
        }
        short8 a0, a1;
        trans4(P, lq, l15, a0, a1);

        // ---- layer 2: W2^T(64x64) @ h1^T ----
        f32x4 ac2[4] = {{0,0,0,0},{0,0,0,0},{0,0,0,0},{0,0,0,0}};
#pragma unroll
        for (int t = 0; t < 4; t++) {
            ac2[t] = __builtin_amdgcn_mfma_f32_16x16x32_bf16(ldsfrag(&sW2T[t][lq][swz][0]),     a0, ac2[t], 0, 0, 0);
            ac2[t] = __builtin_amdgcn_mfma_f32_16x16x32_bf16(ldsfrag(&sW2T[t][4 + lq][swz][0]), a1, ac2[t], 0, 0, 0);
        }
#pragma unroll
        for (int t = 0; t < 4; t++) {
            float4 bb = *(const float4*)&sb2[t * 16 + lq * 4];
            float h0  = fmaxf(ac2[t][0] + bb.x, 0.f);
            float h1v = fmaxf(ac2[t][1] + bb.y, 0.f);
            float h2v = fmaxf(ac2[t][2] + bb.z, 0.f);
            float h3v = fmaxf(ac2[t][3] + bb.w, 0.f);
            P[t][0] = pkbf(h0, h1v);
            P[t][1] = pkbf(h2v, h3v);
        }
        trans4(P, lq, l15, a0, a1);

        // ---- layer 3: W3^T(8x64, zero-padded) @ h2^T ----
        f32x4 aL = {0, 0, 0, 0};
        aL = __builtin_amdgcn_mfma_f32_16x16x32_bf16(ldsfrag(&sW3T[lq][swz][0]),     a0, aL, 0, 0, 0);
        aL = __builtin_amdgcn_mfma_f32_16x16x32_bf16(ldsfrag(&sW3T[4 + lq][swz][0]), a1, aL, 0, 0, 0);
        if (lq < 2) {
            float4 bb = *(const float4*)&sb3[lq * 4];
            float4 lg;
            lg.x = aL[0] + bb.x;
            lg.y = aL[1] + bb.y;
            lg.z = aL[2] + bb.z;
            lg.w = aL[3] + bb.w;
            *(float4*)(logits + e * 8 + lq * 4) = lg;
            unsigned* sm = segmax + (long)esrc * 8 + lq * 4;
            atomicMax(sm + 0, fmap(lg.x));
            atomicMax(sm + 1, fmap(lg.y));
            atomicMax(sm + 2, fmap(lg.z));
            atomicMax(sm + 3, fmap(lg.w));
        }
    }
}

// ---- fused: e=exp(lg-max); denom[src]+=e; agg[src] += e * v[dst] (unnormalized) ----
__global__ void k_agg(const int* __restrict__ eidx,
                      const float* __restrict__ logits,
                      const unsigned* __restrict__ segmax,
                      const float* __restrict__ v,
                      float* __restrict__ denom,
                      float* __restrict__ agg) {
    int t = threadIdx.x;
    int lane = t & 63, wv = t >> 6;
    long e = (long)blockIdx.x * 4 + wv;
    if (e >= NE) return;
    int2 sd = ((const int2*)eidx)[e];
    int o = lane & 7;      // head index j
    int i = lane >> 3;     // value index
    float lg = logits[e * 8 + o];
    float m = funmap(segmax[(long)sd.x * 8 + o]);
    float ex = __expf(lg - m);
    if (i == 0) atomicAdd(&denom[(long)sd.x * 8 + o], ex);
    float val = ex * v[(long)sd.y * 8 + i];
    atomicAdd(&agg[(long)sd.x * 64 + lane], val);
}

// ---- out_pre = (agg/denom)@Wc+bc ; out_final = relu(af + out_pre) ----
__global__ __launch_bounds__(256) void k_out(
    const float* __restrict__ agg, const float* __restrict__ denom,
    const float* __restrict__ Wc, const float* __restrict__ bc,
    const float* __restrict__ af,
    float* __restrict__ out_pre, float* __restrict__ out_final) {
    __shared__ float sWc[64 * 64];
    int t = threadIdx.x;
    for (int i = t; i < 4096; i += 256) sWc[i] = Wc[i];
    __syncthreads();
    int lane = t & 63, wv = t >> 6;
    float bcv = bc[lane];
    long stride = (long)gridDim.x * 4;
    for (long n = (long)blockIdx.x * 4 + wv; n < NA; n += stride) {
        float den = denom[n * 8 + (lane & 7)];
        float rs = (den != 0.f) ? (1.0f / den) : 0.f;   // deg-0 node: agg==0, avoid 0*inf
        float a = agg[n * 64 + lane] * rs;
        float acc = bcv;
#pragma unroll 4
        for (int k = 0; k < 64; k++) acc += __shfl(a, k) * sWc[k * 64 + lane];
        out_pre[n * 64 + lane] = acc;
        out_final[n * 64 + lane] = fmaxf(af[n * 64 + lane] + acc, 0.f);
    }
}

// ---- new_bond = relu([op[dst]+op[src], bond] @ Wb + bb) ----
// Coalesced gather of out_pre rows, summed at loader lane, shfl-redistributed.
__global__ __launch_bounds__(256) void k_bond_out(
    const float* __restrict__ out_pre, const float* __restrict__ bond,
    const int* __restrict__ eidx, const float* __restrict__ Wb,
    const float* __restrict__ bb, float* __restrict__ nbf) {
    __shared__ __align__(16) unsigned short sWbT[4][16][16][8];   // 16 KB
    __shared__ __align__(16) float sbb[64];

    int tid = threadIdx.x;
    for (int idx = tid; idx < 128 * 64; idx += 256) {
        int k = idx >> 6, n = idx & 63, kc = k >> 3;
        sWbT[n >> 4][kc][(n & 15) ^ ((kc & 3) << 1)][k & 7] = f2bf(Wb[idx]);
    }
    if (tid < 64) sbb[tid] = bb[tid];
    __syncthreads();

    int lane = tid & 63, wv = tid >> 6;
    int l15 = lane & 15, lq = lane >> 4;
    int swz = l15 ^ (lq << 1);
    int eL  = lane >> 2;
    int part = lane & 3;
    int srcA = (l15 << 2) + (lq >> 1);
    bool hi  = (lq & 1) != 0;

    long stride = (long)gridDim.x * 4;
    for (long tile = (long)blockIdx.x * 4 + wv; tile < NE / 16; tile += stride) {
        long base = tile * 16;
        long e = base + l15;
        // ---- coalesced gather + sum at loader lane ----
        int2 sd = ((const int2*)eidx)[base + eL];
        const float4* pdq = (const float4*)(out_pre + (long)sd.y * 64) + part * 4;
        const float4* psq = (const float4*)(out_pre + (long)sd.x * 64) + part * 4;
        float4 q0 = add4(pdq[0], psq[0]);
        float4 q1 = add4(pdq[1], psq[1]);
        float4 q2 = add4(pdq[2], psq[2]);
        float4 q3 = add4(pdq[3], psq[3]);
        unsigned uo[8];
        pack8(q0, q1, q2, q3, uo);
        short8 xf0, xf1;
        redist(uo, srcA, hi, xf0, xf1);   // (op[dst]+op[src]) -> k 0..63

        const float* pb = bond + e * 64 + lq * 8;
        float4 c0 = *(const float4*)(pb);
        float4 c1 = *(const float4*)(pb + 4);
        float4 c2 = *(const float4*)(pb + 32);
        float4 c3 = *(const float4*)(pb + 36);
        short8 xf2 = pack_frag(c0, c1);   // bond -> k 64..95
        short8 xf3 = pack_frag(c2, c3);   //         k 96..127

        f32x4 acc[4] = {{0,0,0,0},{0,0,0,0},{0,0,0,0},{0,0,0,0}};
#pragma unroll
        for (int t = 0; t < 4; t++) {
            acc[t] = __builtin_amdgcn_mfma_f32_16x16x32_bf16(ldsfrag(&sWbT[t][lq][swz][0]),      xf0, acc[t], 0, 0, 0);
            acc[t] = __builtin_amdgcn_mfma_f32_16x16x32_bf16(ldsfrag(&sWbT[t][4 + lq][swz][0]),  xf1, acc[t], 0, 0, 0);
            acc[t] = __builtin_amdgcn_mfma_f32_16x16x32_bf16(ldsfrag(&sWbT[t][8 + lq][swz][0]),  xf2, acc[t], 0, 0, 0);
            acc[t] = __builtin_amdgcn_mfma_f32_16x16x32_bf16(ldsfrag(&sWbT[t][12 + lq][swz][0]), xf3, acc[t], 0, 0, 0);
        }
        float* op = nbf + e * 64 + lq * 4;
#pragma unroll
        for (int t = 0; t < 4; t++) {
            float4 bq = *(const float4*)&sbb[t * 16 + lq * 4];
            float4 r;
            r.x = fmaxf(acc[t][0] + bq.x, 0.f);
            r.y = fmaxf(acc[t][1] + bq.y, 0.f);
            r.z = fmaxf(acc[t][2] + bq.z, 0.f);
            r.w = fmaxf(acc[t][3] + bq.w, 0.f);
            *(float4*)(op + t * 16) = r;
        }
    }
}

extern "C" void kernel_launch(void* const* d_in, const int* in_sizes, int n_in,
                              void* d_out, int out_size, void* d_ws, size_t ws_size,
                              hipStream_t stream) {
    const float* af   = (const float*)d_in[0];
    const float* bond = (const float*)d_in[1];
    const int*   eidx = (const int*)d_in[2];
    const float* Wv = (const float*)d_in[3];
    const float* bv = (const float*)d_in[4];
    const float* W1 = (const float*)d_in[5];
    const float* b1 = (const float*)d_in[6];
    const float* W2 = (const float*)d_in[7];
    const float* b2 = (const float*)d_in[8];
    const float* W3 = (const float*)d_in[9];
    const float* b3 = (const float*)d_in[10];
    const float* Wc = (const float*)d_in[11];
    const float* bc = (const float*)d_in[12];
    const float* Wb = (const float*)d_in[13];
    const float* bb = (const float*)d_in[14];

    float* out_final = (float*)d_out;                  // N*64
    float* nbf       = (float*)d_out + (long)NA * 64;  // E*64

    float* ws = (float*)d_ws;
    float*    v       = ws;                         // N*8
    unsigned* segmax  = (unsigned*)(ws + 800000);   // N*8
    float*    denom   = ws + 1600000;               // N*8
    float*    logits  = ws + 2400000;               // E*8
    float*    agg     = ws + 8800000;               // N*64
    float*    out_pre = ws + 15200000;              // N*64

    // one memset covers segmax (800k u32) + denom (800k f32), contiguous
    hipMemsetAsync((void*)segmax, 0, (size_t)1600000 * 4, stream);
    hipMemsetAsync((void*)agg, 0, (size_t)6400000 * 4, stream);

    k_v<<<(NA * 8 + 255) / 256, 256, 0, stream>>>(af, Wv, bv, v);

    k_edge_mlp<<<1024, 256, 0, stream>>>(af, bond, eidx, W1, b1, W2, b2, W3, b3,
                                         logits, segmax);

    k_agg<<<NE / 4, 256, 0, stream>>>(eidx, logits, segmax, v, denom, agg);

    k_out<<<512, 256, 0, stream>>>(agg, denom, Wc, bc, af, out_pre, out_final);

    k_bond_out<<<2048, 256, 0, stream>>>(out_pre, bond, eidx, Wb, bb, nbf);
}